// Round 1
// 67.677 us; speedup vs baseline: 1.0183x; 1.0183x over previous
//
#include <hip/hip_runtime.h>

#define IMAGE   128
#define NLINES  32
#define NCURVE  64      // N_LINES * N_SEGMENTS
#define NSUB    9       // N_SAMPLES - 1
#define PIX     (IMAGE*IMAGE)
#define BS      4
#define NCHUNK  8       // curve chunks (one per wave)

#if __has_builtin(__builtin_amdgcn_exp2f)
#define EXP2F(x) __builtin_amdgcn_exp2f(x)
#else
#define EXP2F(x) exp2f(x)
#endif

// Block = 512 threads = 8 waves; block covers 256 pixels (a 2-row y-band) of one
// batch image. Wave 7 ballots which curves can touch this band (y-hull + 0.45*r
// margin => skipped intensity < 8e-8) and writes a compacted, order-preserving
// active-curve list. Each wave composites a contiguous 1/8 slice of that list
// (contiguity keeps the per-chunk partial-transmittance merge exact), so culling
// both removes work AND stays load-balanced across the block barrier.
// Pixels per lane factor as 2 rows x 2 column-halves: only 2 distinct dY and
// 2 distinct dX per subsegment, cutting the inner body to ~36 VALU ops.
__global__ __launch_bounds__(512, 2)
void render_kernel(const float* __restrict__ pos,   // (4, 32, 10)
                   const float* __restrict__ rad,   // (4, 32, 1)
                   const float* __restrict__ col,   // (4, 32, 3)
                   const float* __restrict__ bg,    // (4, 3)
                   float* __restrict__ out)         // (4, 3, 128, 128)
{
    __shared__ float4 s_sub4[NCURVE*NSUB];   // a0, a1, v0, v1   (coord0=y, coord1=x)
    __shared__ float2 s_sub2[NCURVE*NSUB];   // w0 = v0*rvv, w1 = v1*rvv
    __shared__ float4 s_cur[NCURVE];         // sqrt(log2e)/(r^2*0.05), R, G, B
    __shared__ int    s_active[NCURVE];      // compacted active curve ids (ascending)
    __shared__ unsigned long long s_mask;    // active bitmask (diagnostic/popcount)
    __shared__ float4 s_part[NCHUNK*256];    // [chunk][k*64+lane] partial (C, T)

    const int tid  = threadIdx.x;
    const int b    = blockIdx.x >> 6;        // 64 tile-blocks per batch
    const int tile = blockIdx.x & 63;        // 2-row band of 256 pixels

    const float yb0 = -1.0f + (float)(tile*2) * (2.0f/127.0f);
    const float yb1 = yb0 + (2.0f/127.0f);

    // ---- cooperative setup: 576 sub-segments for this batch ----
    for (int e = tid; e < NCURVE*NSUB; e += 512) {
        const int n    = e / NSUB;
        const int j    = e - n*NSUB;
        const int line = n >> 1;
        const int seg  = n & 1;
        const float* P = pos + (b*NLINES + line)*10;
        float c0a, c0b, c1a, c1b, c2a, c2b;
        if (seg == 0) {                      // p0, p1, p2
            c0a = P[0]; c0b = P[1];
            c1a = P[2]; c1b = P[3];
            c2a = P[4]; c2b = P[5];
        } else {                             // p2, 2*p2 - p3, p4
            const float q2a = P[4], q2b = P[5];
            const float q3a = P[6], q3b = P[7];
            c0a = q2a;             c0b = q2b;
            c1a = 2.0f*q2a - q3a;  c1b = 2.0f*q2b - q3b;
            c2a = P[8];            c2b = P[9];
        }
        const float t0 = (float)j     * (1.0f/9.0f);
        const float t1 = (float)(j+1) * (1.0f/9.0f);
        float aa, ab, ba, bb;
        {
            const float mt = 1.0f - t0;
            const float w0 = mt*mt, w1 = 2.0f*t0*mt, w2 = t0*t0;
            aa = w0*c0a + w1*c1a + w2*c2a;
            ab = w0*c0b + w1*c1b + w2*c2b;
        }
        {
            const float mt = 1.0f - t1;
            const float w0 = mt*mt, w1 = 2.0f*t1*mt, w2 = t1*t1;
            ba = w0*c0a + w1*c1a + w2*c2a;
            bb = w0*c0b + w1*c1b + w2*c2b;
        }
        const float v0 = ba - aa, v1 = bb - ab;
        const float rvv = 1.0f / (v0*v0 + v1*v1 + 1e-10f);
        s_sub4[e] = make_float4(aa, ab, v0, v1);
        s_sub2[e] = make_float2(v0*rvv, v1*rvv);
    }
    // ---- wave 7: per-curve color/scale + band-cull ballot + compaction ----
    if (tid >= 448) {
        const int n    = tid - 448;          // lanes 0..63 of wave 7
        const int line = n >> 1;
        const int seg  = n & 1;
        const float* P = pos + (b*NLINES + line)*10;
        float a0, a1, a2;                    // control-point coord0 (y) values
        if (seg == 0) { a0 = P[0]; a1 = P[2];             a2 = P[4]; }
        else          { a0 = P[4]; a1 = 2.0f*P[4] - P[6]; a2 = P[8]; }
        const float r = rad[b*NLINES + line];
        const float m = 0.45f * r;           // I < 8e-8 beyond this distance
        const float lo = fminf(a0, fminf(a1, a2)) - m;
        const float hi = fmaxf(a0, fmaxf(a1, a2)) + m;
        const bool act = (lo <= yb1) && (hi >= yb0);
        const unsigned long long mask = __ballot(act);
        const int lane = tid & 63;
        const int rank = __popcll(mask & ((1ull << lane) - 1ull));
        if (act) s_active[rank] = n;
        if (lane == 0) s_mask = mask;
        s_cur[n] = make_float4(1.2011224087864498f / (r*r*0.05f), // sqrt(log2e)/sigma
                               col[(b*NLINES + line)*3 + 0],
                               col[(b*NLINES + line)*3 + 1],
                               col[(b*NLINES + line)*3 + 2]);
    }
    __syncthreads();

    // ---- hot loop: contiguous slice of active curves per wave, 4 px/lane ----
    const int lane  = tid & 63;
    const int chunk = tid >> 6;              // wave id, wave-uniform
    const int A     = __popcll(s_mask);
    const int start = (chunk * A) >> 3;
    const int end   = ((chunk + 1) * A) >> 3;

    const float x0 = -1.0f + (float)lane        * (2.0f/127.0f);
    const float x1 = -1.0f + (float)(lane + 64) * (2.0f/127.0f);

    float aR[4], aG[4], aB[4], T[4];
    #pragma unroll
    for (int k = 0; k < 4; ++k) { aR[k] = 0.0f; aG[k] = 0.0f; aB[k] = 0.0f; T[k] = 1.0f; }

    #pragma unroll 1
    for (int ii = start; ii < end; ++ii) {
        const int n    = s_active[ii];       // wave-uniform
        const int base = n*NSUB;
        float edt2[4];
        #pragma unroll
        for (int k = 0; k < 4; ++k) edt2[k] = 3.4e38f;
        #pragma unroll
        for (int j = 0; j < NSUB; ++j) {     // full unroll: 18 independent ds_reads
            const float4 s = s_sub4[base + j];
            const float2 w = s_sub2[base + j];
            const float dY0 = yb0 - s.x;
            const float dY1 = yb1 - s.x;
            const float dX0 = x0  - s.y;
            const float dX1 = x1  - s.y;
            #pragma unroll
            for (int k = 0; k < 4; ++k) {    // k = (row<<1)|colhalf
                const float dA = (k & 2) ? dY1 : dY0;
                const float dB = (k & 1) ? dX1 : dX0;
                const float tp = __builtin_amdgcn_fmed3f(fmaf(dB, w.y, dA*w.x), 0.0f, 1.0f);
                const float e0 = fmaf(-tp, s.z, dA);
                const float e1 = fmaf(-tp, s.w, dB);
                edt2[k] = fminf(edt2[k], fmaf(e0, e0, e1*e1));
            }
        }
        const float4 cu = s_cur[n];
        #pragma unroll
        for (int k = 0; k < 4; ++k) {
            const float xs = edt2[k] * cu.x;
            const float I  = EXP2F(-(xs*xs));   // exp(-(edt2/sigma)^2), log2e folded
            const float wI = I * T[k];
            aR[k] = fmaf(cu.y, wI, aR[k]);
            aG[k] = fmaf(cu.z, wI, aG[k]);
            aB[k] = fmaf(cu.w, wI, aB[k]);
            T[k] *= (1.0f - I);                 // +1e-10 dropped: error <= 1e-8
        }
    }
    #pragma unroll
    for (int k = 0; k < 4; ++k)
        s_part[chunk*256 + k*64 + lane] = make_float4(aR[k], aG[k], aB[k], T[k]);
    __syncthreads();

    // ---- merge the 8 chunk-partials per pixel, in curve order ----
    if (tid < 256) {
        float4 acc = s_part[tid];
        float C0 = acc.x, C1 = acc.y, C2 = acc.z, Tt = acc.w;
        #pragma unroll
        for (int c = 1; c < NCHUNK; ++c) {
            const float4 q = s_part[c*256 + tid];
            C0 = fmaf(Tt, q.x, C0);
            C1 = fmaf(Tt, q.y, C1);
            C2 = fmaf(Tt, q.z, C2);
            Tt *= q.w;
        }
        C0 = fmaf(Tt, bg[b*3+0], C0);
        C1 = fmaf(Tt, bg[b*3+1], C1);
        C2 = fmaf(Tt, bg[b*3+2], C2);
        const int po = tile*256 + tid;
        out[(b*3+0)*PIX + po] = fminf(fmaxf(C0, 0.0f), 1.0f);
        out[(b*3+1)*PIX + po] = fminf(fmaxf(C1, 0.0f), 1.0f);
        out[(b*3+2)*PIX + po] = fminf(fmaxf(C2, 0.0f), 1.0f);
    }
}

extern "C" void kernel_launch(void* const* d_in, const int* in_sizes, int n_in,
                              void* d_out, int out_size, void* d_ws, size_t ws_size,
                              hipStream_t stream) {
    const float* pos = (const float*)d_in[0];
    const float* rad = (const float*)d_in[1];
    const float* col = (const float*)d_in[2];
    const float* bg  = (const float*)d_in[3];
    float* out = (float*)d_out;

    // 4 batches * 64 two-row bands of 256 pixels; 8 curve-chunk waves per block
    render_kernel<<<dim3(BS*64), dim3(512), 0, stream>>>(pos, rad, col, bg, out);
}